// Round 11
// baseline (187.793 us; speedup 1.0000x reference)
//
#include <hip/hip_runtime.h>
#include <hip/hip_bf16.h>

#define B_N 16384
#define D_N 512
#define M_N 16

typedef __attribute__((ext_vector_type(4)))  float f32x4;
typedef __attribute__((ext_vector_type(16))) float f32x16;
typedef __attribute__((ext_vector_type(8)))  short s16x8;
typedef __attribute__((ext_vector_type(4)))  unsigned short u16x4;

__device__ __forceinline__ short bf16_of(float f) {
  union { float f; unsigned u; } v; v.f = f;
  unsigned r = v.u + 0x7fffu + ((v.u >> 16) & 1u);  // RNE
  return (short)(r >> 16);
}
__device__ __forceinline__ float f32_of_bf16(unsigned short u) {
  union { unsigned u; float f; } v; v.u = ((unsigned)u) << 16; return v.f;
}
__device__ __forceinline__ void gload_lds16(const void* g, void* l) {
  __builtin_amdgcn_global_load_lds(
      (const __attribute__((address_space(1))) unsigned*)g,
      (__attribute__((address_space(3))) unsigned*)l, 16, 0, 0);
}

// ---------------------------------------------------------------------------
// Kernel 1 (fused): Psib[m][etile][dc][kq][erow]x16B = bf16(Psi[m][d][e])
// in MFMA-fragment order (conflict-free ds_read, no swizzle), AND
// wT[d,m] = sum_e Psi[m,d,e]*gt[m,e] (f32 exact path for gates).
// grid (8 d-tiles, 16 m) x 256;  blockIdx.x = dc.
// ---------------------------------------------------------------------------
__global__ void k_trw(const float* __restrict__ Psi, const float* __restrict__ gt,
                      short* __restrict__ Psib, float* __restrict__ wT) {
  int m = blockIdx.y, bx = blockIdx.x, d0 = bx << 6;
  __shared__ float tile[64][65];
  __shared__ float gs[D_N];
  int t = threadIdx.x;
  for (int i = t; i < D_N; i += 256) gs[i] = gt[m * D_N + i];
  int r = t >> 2, q = t & 3;
  float wacc = 0.f;
  const float* src = Psi + (size_t)m * D_N * D_N;
  for (int e0 = 0; e0 < D_N; e0 += 64) {
    __syncthreads();
    #pragma unroll
    for (int j = 0; j < 4; ++j) {
      int idx = t + (j << 8);
      int rr = idx >> 4, c4 = idx & 15;
      *(f32x4*)&tile[rr][c4 * 4] = *(const f32x4*)(src + (size_t)(d0 + rr) * D_N + e0 + c4 * 4);
    }
    __syncthreads();
    #pragma unroll
    for (int k = 0; k < 16; ++k) wacc += tile[r][q * 16 + k] * gs[e0 + q * 16 + k];
    #pragma unroll
    for (int it = 0; it < 2; ++it) {
      int idx = t + (it << 8);          // 512 units = 64 e-rows x 8 kq
      int el = idx >> 3, jb = idx & 7;
      int e = e0 + el;
      s16x8 o;
      #pragma unroll
      for (int k = 0; k < 8; ++k) o[k] = bf16_of(tile[jb * 8 + k][el]);
      // off(shorts) = ((m*4 + etile)*8 + dc)*8192 + kq*1024 + erow*8
      size_t off = ((size_t)((((m << 2) + (e >> 7)) << 3) | bx) << 13)
                 + (jb << 10) + ((e & 127) << 3);
      *(s16x8*)(Psib + off) = o;
    }
  }
  wacc += __shfl_xor(wacc, 1);
  wacc += __shfl_xor(wacc, 2);
  if (q == 0) wT[(d0 + r) * M_N + m] = wacc;
}

// ---------------------------------------------------------------------------
// Kernel 2 (fused): gates (bf16) + bf16 z in MFMA-fragment order:
// zb[btile][dc][kq][brow]x16B.  One z read.  grid B/16 x 256.
// ---------------------------------------------------------------------------
__global__ void k_gz(const float* __restrict__ z, const float* __restrict__ wT,
                     short* __restrict__ zb, unsigned short* __restrict__ gatesb) {
  __shared__ float zs[16][D_N];
  int t = threadIdx.x;
  size_t b0 = (size_t)blockIdx.x * 16;
  #pragma unroll
  for (int j = 0; j < 8; ++j) {
    int idx = t + (j << 8);
    int r = idx >> 7, c4 = idx & 127;
    *(f32x4*)&zs[r][c4 * 4] = *(const f32x4*)(z + (b0 + r) * D_N + c4 * 4);
  }
  __syncthreads();
  int r = t >> 4, m = t & 15;
  float s0 = 0.f, s1 = 0.f, s2 = 0.f, s3 = 0.f;
  #pragma unroll 4
  for (int e = 0; e < D_N; e += 4) {
    s0 += zs[r][e + 0] * wT[(e + 0) * M_N + m];
    s1 += zs[r][e + 1] * wT[(e + 1) * M_N + m];
    s2 += zs[r][e + 2] * wT[(e + 2) * M_N + m];
    s3 += zs[r][e + 3] * wT[(e + 3) * M_N + m];
  }
  float s = (s0 + s1) + (s2 + s3);
  float sig = 1.f / (1.f + expf(-s));
  gatesb[(b0 + r) * M_N + m] = (unsigned short)bf16_of(fmaxf(2.f * sig - 1.f, 0.f));
  // fragment-order write: unit u = c*16 + rr  (c = dc*8+kq, 0..63)
  #pragma unroll
  for (int j = 0; j < 4; ++j) {
    int u = t + (j << 8);
    int rr = u & 15, c = u >> 4;
    s16x8 o;
    #pragma unroll
    for (int k = 0; k < 8; ++k) o[k] = bf16_of(zs[rr][(c << 3) + k]);
    size_t off = ((size_t)(b0 >> 7) << 17) + ((size_t)(c >> 3) << 14)
               + ((c & 7) << 11) + ((((int)(b0 & 127)) + rr) << 4);
    *(s16x8*)((char*)zb + off) = o;
  }
}

// ---------------------------------------------------------------------------
// Kernel 3: GEMM dz^T = sum_m g_m*(Psi_m^T @ z^T) with 32x32x16 MFMA.
// 128b x 128e tile, 8 waves (wr=b-quad, wc=e-half), wave-tile 32b x 64e
// (2 x 32x32 output tiles, one shared accm).  Fragment-order LDS (zero
// conflicts, imm-offset ds_reads).  NBUF=3 B + counted vmcnt (never 0
// mid-loop); single A buffer staged at m==1.  2 blocks/CU.
// LDS: A 16KB @0 | B 3x16KB @16384 | gates f32 8KB @65536.
// ---------------------------------------------------------------------------
__global__ __launch_bounds__(512, 4) void k_gemm(
    const char* __restrict__ zb, const unsigned short* __restrict__ gatesb,
    const char* __restrict__ pb, float* __restrict__ dz) {
  __shared__ __align__(128) char smem[73728];
  float* glf = (float*)(smem + 65536);

  const int tid = threadIdx.x;
  const int lane = tid & 63;
  const int wid = tid >> 6;
  const int wr = wid >> 1;               // b-quad: 4 x 32 rows
  const int wc = wid & 1;                // e-half: 2 x 64 cols
  const int bid = blockIdx.x;
  const int xcd = bid & 7;
  const int g8 = bid >> 3;
  const int bcol = g8 & 3;
  const int brow = xcd * 16 + (g8 >> 2); // A-centric XCD map (z L2-resident)

  // ---- gates -> LDS [m][128 rows] f32
  {
    int row = tid >> 2, g4 = tid & 3;
    u16x4 gv = *(const u16x4*)(gatesb + ((size_t)(brow * 128 + row) << 4) + (g4 << 2));
    #pragma unroll
    for (int k = 0; k < 4; ++k)
      glf[(g4 * 4 + k) * 128 + row] = f32_of_bf16(gv[k]);
  }

  const int lnoff = (wid << 11) + (lane << 4);
  const char* zsrc = zb + (size_t)brow * 131072 + lnoff;
  const char* bsrc = pb + ((size_t)bcol << 17) + lnoff;

  auto stageA = [&](int dc) {            // 16KB tile, 2 loads/wave
    const char* g = zsrc + (dc << 14);
    char* l = smem + (wid << 11);
    gload_lds16(g, l);
    gload_lds16(g + 1024, l + 1024);
  };
  auto stageB = [&](int m, int dc, int q) {
    const char* g = bsrc + ((size_t)m << 19) + (dc << 14);
    char* l = smem + 16384 + (q << 14) + (wid << 11);
    gload_lds16(g, l);
    gload_lds16(g + 1024, l + 1024);
  };

  const int lhalf = lane >> 5;           // k-half
  const int lrow32 = lane & 31;
  const int zoff = (lhalf << 11) + ((wr * 32 + lrow32) << 4);  // + ks*4096
  const int poff = (lhalf << 11) + ((wc * 64 + lrow32) << 4);  // + t*512 + ks*4096

  f32x16 acc0 = {}, acc1 = {};
  s16x8 zf[4];
  const f32x16 FZ = {};

  // ---- prologue
  stageA(0);
  stageB(0, 0, 0);
  stageB(1, 0, 1);
  asm volatile("s_waitcnt vmcnt(0) lgkmcnt(0)" ::: "memory");
  __builtin_amdgcn_s_barrier();

  int q = 0;
  #pragma unroll 1
  for (int s = 0; s < 128; ++s) {
    const int m = s & 15, dc = s >> 4;
    int q2 = q + 2; if (q2 >= 3) q2 -= 3;

    // ---- issue stages first (land 2 steps / 15 steps later)
    if (s + 2 < 128) stageB((s + 2) & 15, (s + 2) >> 4, q2);
    const bool aw = (m == 1) && (dc < 7);
    if (aw) stageA(dc + 1);

    // ---- z frags once per d-chunk
    if (m == 0) {
      zf[0] = *(const s16x8*)(smem + zoff);
      zf[1] = *(const s16x8*)(smem + zoff + 4096);
      zf[2] = *(const s16x8*)(smem + zoff + 8192);
      zf[3] = *(const s16x8*)(smem + zoff + 12288);
    }
    float g = glf[(m << 7) + wr * 32 + lrow32];
    const char* bb = smem + 16384 + (q << 14);

    // ---- e-tile 0: 4 frag reads + 4 MFMA + fold
    {
      s16x8 p0 = *(const s16x8*)(bb + poff);
      s16x8 p1 = *(const s16x8*)(bb + poff + 4096);
      s16x8 p2 = *(const s16x8*)(bb + poff + 8192);
      s16x8 p3 = *(const s16x8*)(bb + poff + 12288);
      __builtin_amdgcn_s_setprio(1);
      f32x16 accm = __builtin_amdgcn_mfma_f32_32x32x16_bf16(p0, zf[0], FZ, 0, 0, 0);
      accm = __builtin_amdgcn_mfma_f32_32x32x16_bf16(p1, zf[1], accm, 0, 0, 0);
      accm = __builtin_amdgcn_mfma_f32_32x32x16_bf16(p2, zf[2], accm, 0, 0, 0);
      accm = __builtin_amdgcn_mfma_f32_32x32x16_bf16(p3, zf[3], accm, 0, 0, 0);
      __builtin_amdgcn_s_setprio(0);
      #pragma unroll
      for (int i = 0; i < 16; ++i) acc0[i] = fmaf(g, accm[i], acc0[i]);
    }
    // ---- e-tile 1
    {
      s16x8 p0 = *(const s16x8*)(bb + poff + 512);
      s16x8 p1 = *(const s16x8*)(bb + poff + 512 + 4096);
      s16x8 p2 = *(const s16x8*)(bb + poff + 512 + 8192);
      s16x8 p3 = *(const s16x8*)(bb + poff + 512 + 12288);
      __builtin_amdgcn_s_setprio(1);
      f32x16 accm = __builtin_amdgcn_mfma_f32_32x32x16_bf16(p0, zf[0], FZ, 0, 0, 0);
      accm = __builtin_amdgcn_mfma_f32_32x32x16_bf16(p1, zf[1], accm, 0, 0, 0);
      accm = __builtin_amdgcn_mfma_f32_32x32x16_bf16(p2, zf[2], accm, 0, 0, 0);
      accm = __builtin_amdgcn_mfma_f32_32x32x16_bf16(p3, zf[3], accm, 0, 0, 0);
      __builtin_amdgcn_s_setprio(0);
      #pragma unroll
      for (int i = 0; i < 16; ++i) acc1[i] = fmaf(g, accm[i], acc1[i]);
    }

    // ---- counted waits: need B(s+1) landed; never drain mid-loop
    if (s < 127) {
      if (s >= 126)
        asm volatile("s_waitcnt vmcnt(0)" ::: "memory");
      else if ((m == 1 || m == 2) && dc < 7)
        asm volatile("s_waitcnt vmcnt(4)" ::: "memory");  // A + B(s+2) in flight
      else
        asm volatile("s_waitcnt vmcnt(2)" ::: "memory");  // B(s+2) in flight
      __builtin_amdgcn_s_barrier();
    }
    q = (q + 1 == 3) ? 0 : q + 1;
  }

  // ---- epilogue: D row=(reg&3)+8*(reg>>2)+4*lhalf (=e), col=lane&31 (=b)
  {
    size_t bglob = (size_t)brow * 128 + wr * 32 + lrow32;
    int ebase = bcol * 128 + wc * 64 + (lhalf << 2);
    float* out = dz + bglob * D_N + ebase;
    #pragma unroll
    for (int qq = 0; qq < 4; ++qq) {
      f32x4 v = {acc0[4 * qq + 0], acc0[4 * qq + 1], acc0[4 * qq + 2], acc0[4 * qq + 3]};
      *(f32x4*)(out + qq * 8) = v;
    }
    #pragma unroll
    for (int qq = 0; qq < 4; ++qq) {
      f32x4 v = {acc1[4 * qq + 0], acc1[4 * qq + 1], acc1[4 * qq + 2], acc1[4 * qq + 3]};
      *(f32x4*)(out + 32 + qq * 8) = v;
    }
  }
}

// ---------------------------------------------------------------------------
extern "C" void kernel_launch(void* const* d_in, const int* in_sizes, int n_in,
                              void* d_out, int out_size, void* d_ws, size_t ws_size,
                              hipStream_t stream) {
  const float* z   = (const float*)d_in[1];
  const float* Psi = (const float*)d_in[2];
  const float* gt  = (const float*)d_in[3];
  float* dz = (float*)d_out;

  // ws: wT 32KB | gatesb 512KB | Psib 8MB | zb16 16MB  (~24.5MB)
  float* wT = (float*)d_ws;
  unsigned short* gatesb = (unsigned short*)((char*)d_ws + 32768);
  short* Psib = (short*)((char*)d_ws + 32768 + 524288);
  short* zb16 = Psib + (size_t)M_N * D_N * D_N;

  k_trw <<<dim3(8, M_N), dim3(256), 0, stream>>>(Psi, gt, Psib, wT);
  k_gz  <<<dim3(B_N / 16), dim3(256), 0, stream>>>(z, wT, zb16, gatesb);
  k_gemm<<<dim3(512), dim3(512), 0, stream>>>((const char*)zb16, gatesb,
                                              (const char*)Psib, dz);
}

// Round 12
// 178.970 us; speedup vs baseline: 1.0493x; 1.0493x over previous
//
#include <hip/hip_runtime.h>
#include <hip/hip_bf16.h>

#define B_N 16384
#define D_N 512
#define M_N 16

typedef __attribute__((ext_vector_type(4))) float  f32x4;
typedef __attribute__((ext_vector_type(2))) float  f32x2;
typedef __attribute__((ext_vector_type(8))) short  s16x8;
typedef __attribute__((ext_vector_type(4))) unsigned short u16x4;

__device__ __forceinline__ short bf16_of(float f) {
  union { float f; unsigned u; } v; v.f = f;
  unsigned r = v.u + 0x7fffu + ((v.u >> 16) & 1u);  // RNE
  return (short)(r >> 16);
}
__device__ __forceinline__ float f32_of_bf16(unsigned short u) {
  union { unsigned u; float f; } v; v.u = ((unsigned)u) << 16; return v.f;
}
__device__ __forceinline__ void gload_lds16(const void* g, void* l) {
  __builtin_amdgcn_global_load_lds(
      (const __attribute__((address_space(1))) unsigned*)g,
      (__attribute__((address_space(3))) unsigned*)l, 16, 0, 0);
}

#define MFMA_ACC(d, x, y) d = __builtin_amdgcn_mfma_f32_16x16x32_bf16(x, y, d, 0, 0, 0)
#define MFMA_Z(d, x, y)   d = __builtin_amdgcn_mfma_f32_16x16x32_bf16(x, y, FZERO, 0, 0, 0)

// ---------------------------------------------------------------------------
// Kernel 1 (fused): Psib[m][e][d] = bf16(Psi[m][d][e]) pre-swizzled, AND
// wT[d,m] = sum_e Psi[m,d,e]*gt[m,e] (f32 exact path for gates).
// ---------------------------------------------------------------------------
__global__ void k_trw(const float* __restrict__ Psi, const float* __restrict__ gt,
                      short* __restrict__ Psib, float* __restrict__ wT) {
  int m = blockIdx.y, d0 = blockIdx.x << 6;
  __shared__ float tile[64][65];
  __shared__ float gs[D_N];
  int t = threadIdx.x;
  for (int i = t; i < D_N; i += 256) gs[i] = gt[m * D_N + i];
  int r = t >> 2, q = t & 3;
  float wacc = 0.f;
  const float* src = Psi + (size_t)m * D_N * D_N;
  short* dst = Psib + (size_t)m * D_N * D_N;
  for (int e0 = 0; e0 < D_N; e0 += 64) {
    __syncthreads();
    #pragma unroll
    for (int j = 0; j < 4; ++j) {
      int idx = t + (j << 8);
      int rr = idx >> 4, c4 = idx & 15;
      *(f32x4*)&tile[rr][c4 * 4] = *(const f32x4*)(src + (size_t)(d0 + rr) * D_N + e0 + c4 * 4);
    }
    __syncthreads();
    #pragma unroll
    for (int k = 0; k < 16; ++k) wacc += tile[r][q * 16 + k] * gs[e0 + q * 16 + k];
    #pragma unroll
    for (int it = 0; it < 2; ++it) {
      int idx = t + (it << 8);
      int el = idx >> 3, jb = idx & 7;
      int e = e0 + el;
      s16x8 o;
      #pragma unroll
      for (int k = 0; k < 8; ++k) o[k] = bf16_of(tile[jb * 8 + k][el]);
      int db = jb ^ (e & 7);
      *(s16x8*)(dst + (size_t)e * D_N + d0 + db * 8) = o;
    }
  }
  wacc += __shfl_xor(wacc, 1);
  wacc += __shfl_xor(wacc, 2);
  if (q == 0) wT[(d0 + r) * M_N + m] = wacc;
}

// ---------------------------------------------------------------------------
// Kernel 2 (fused): gates (bf16) + pre-swizzled bf16 z, one z read.
// ---------------------------------------------------------------------------
__global__ void k_gz(const float* __restrict__ z, const float* __restrict__ wT,
                     short* __restrict__ zb, unsigned short* __restrict__ gatesb) {
  __shared__ float zs[16][D_N];
  int t = threadIdx.x;
  size_t b0 = (size_t)blockIdx.x * 16;
  #pragma unroll
  for (int j = 0; j < 8; ++j) {
    int idx = t + (j << 8);
    int r = idx >> 7, c4 = idx & 127;
    *(f32x4*)&zs[r][c4 * 4] = *(const f32x4*)(z + (b0 + r) * D_N + c4 * 4);
  }
  __syncthreads();
  int r = t >> 4, m = t & 15;
  float s0 = 0.f, s1 = 0.f, s2 = 0.f, s3 = 0.f;
  #pragma unroll 4
  for (int e = 0; e < D_N; e += 4) {
    s0 += zs[r][e + 0] * wT[(e + 0) * M_N + m];
    s1 += zs[r][e + 1] * wT[(e + 1) * M_N + m];
    s2 += zs[r][e + 2] * wT[(e + 2) * M_N + m];
    s3 += zs[r][e + 3] * wT[(e + 3) * M_N + m];
  }
  float s = (s0 + s1) + (s2 + s3);
  float sig = 1.f / (1.f + expf(-s));
  gatesb[(b0 + r) * M_N + m] = (unsigned short)bf16_of(fmaxf(2.f * sig - 1.f, 0.f));
  #pragma unroll
  for (int j = 0; j < 4; ++j) {
    int idx = t + (j << 8);
    int rr = idx >> 6, blk = idx & 63;
    int chunk = blk >> 3, ib = blk & 7;
    int sb = ib ^ (rr & 7);
    const float* sp = &zs[rr][chunk * 64 + sb * 8];
    s16x8 o;
    #pragma unroll
    for (int k = 0; k < 8; ++k) o[k] = bf16_of(sp[k]);
    *(s16x8*)(zb + (b0 + rr) * D_N + blk * 8) = o;
  }
}

// ---------------------------------------------------------------------------
// Kernel 3: GEMM dz^T = sum_m g_m*(Psi_m^T @ z^T).  Round 12 = round 10 with
// the wave grid TRANSPOSED to 2b x 4e (wave-tile 64b x 32e): each B-fragment
// now read by 2 waves instead of 4 -> B LDS reads halved (the round-10
// co-limiter).  16x16x32 MFMA, 8 independent accm chains, per-step
// vmcnt(0)+barrier, NBUF=2, 2 blocks/CU, A-centric XCD map.  z-frag prefetch
// at m==15 from the just-landed next-dc A buffer.
// LDS 72KB: A 2x16KB @0 | B 2x16KB @32768 | gates f32 8KB @65536.
// ---------------------------------------------------------------------------
__global__ __launch_bounds__(512, 4) void k_gemm(
    const char* __restrict__ zb, const unsigned short* __restrict__ gatesb,
    const char* __restrict__ pb, float* __restrict__ dz) {
  __shared__ __align__(128) char smem[73728];
  float* glf = (float*)(smem + 65536);

  const int tid = threadIdx.x;
  const int lane = tid & 63;
  const int wid = tid >> 6;            // 0..7
  const int wr = wid >> 2;             // b-half: 2 x 64 rows
  const int wc = wid & 3;              // e-quarter: 4 x 32 cols
  const int bid = blockIdx.x;          // 512 blocks
  const int xcd = bid & 7;
  const int g8 = bid >> 3;             // 0..63
  const int bcol = g8 & 3;
  const int brow = xcd * 16 + (g8 >> 2);  // 16 brow-slabs/XCD -> 2MB z, L2-fit

  // ---- gates -> LDS [m][128 rows] f32
  {
    int row = tid >> 2, g4 = tid & 3;
    u16x4 gv = *(const u16x4*)(gatesb + ((size_t)(brow * 128 + row) << 4) + (g4 << 2));
    #pragma unroll
    for (int k = 0; k < 4; ++k)
      glf[(g4 * 4 + k) * 128 + row] = f32_of_bf16(gv[k]);
  }

  const int rsub = lane >> 3, cbyte = (lane & 7) << 4;

  auto stageA = [&](int ab, int dc) {     // 2 loads: 128 rows x 128B d-chunk
    #pragma unroll
    for (int j = 0; j < 2; ++j) {
      const char* g = zb + (((size_t)(brow * 128 + wid * 8 + j * 64 + rsub)) << 10)
                      + (dc << 7) + cbyte;
      gload_lds16(g, smem + ab * 16384 + (wid << 10) + (j << 13));
    }
  };
  auto stageB = [&](int m, int dc, int qb) {  // 2 loads: 128 e-rows x 128B
    #pragma unroll
    for (int j = 0; j < 2; ++j) {
      const char* g = pb + (((size_t)(m * 512 + bcol * 128 + wid * 8 + j * 64 + rsub)) << 10)
                      + (dc << 7) + cbyte;
      gload_lds16(g, smem + 32768 + qb * 16384 + (wid << 10) + (j << 13));
    }
  };

  const int lrow = lane & 15;
  const int kq16 = (((lane >> 4) << 4)) ^ ((lrow & 7) << 4);
  const int offY = ((wr * 64 + lrow) << 7) + kq16;   // z frags (y op), +j*2048
  const int offX = ((wc * 32 + lrow) << 7) + kq16;   // Psi frags (x op), +i*2048
  const int grow = wr * 64 + lrow;                   // gate row base, +j*16

  f32x4 acc[2][4] = {};
  f32x4 accm[2][4];
  s16x8 areg[4][2];
  const f32x4 FZERO = {0.f, 0.f, 0.f, 0.f};

  // ---- prologue: A(dc0), B(s=0); drain (covers gate ds_writes too); barrier
  stageA(0, 0);
  stageB(0, 0, 0);
  asm volatile("s_waitcnt vmcnt(0) lgkmcnt(0)" ::: "memory");
  __builtin_amdgcn_s_barrier();

  // ---- initial z frags (dc=0, buffer 0)
  #pragma unroll
  for (int j = 0; j < 4; ++j) {
    areg[j][0] = *(const s16x8*)(smem + (offY + j * 2048));
    areg[j][1] = *(const s16x8*)(smem + ((offY + j * 2048) ^ 64));
  }

  #pragma unroll 1
  for (int s = 0; s < 128; ++s) {
    const int m = s & 15, dc = s >> 4;

    // ---- issue next-tile stages first (latency cover under this step)
    if (s < 127) stageB((s + 1) & 15, (s + 1) >> 4, (s + 1) & 1);
    if (m == 14 && dc < 7) stageA((dc & 1) ^ 1, dc + 1);

    float g0 = glf[(m << 7) + grow];
    float g1 = glf[(m << 7) + grow + 16];
    float g2 = glf[(m << 7) + grow + 32];
    float g3 = glf[(m << 7) + grow + 48];

    const char* bbase = smem + 32768 + (s & 1) * 16384;
    // ---- ks0: 2 frag reads + 8 MFMA (C=0, 8 independent chains)
    {
      s16x8 p0 = *(const s16x8*)(bbase + (offX));
      s16x8 p1 = *(const s16x8*)(bbase + (offX + 2048));
      __builtin_amdgcn_s_setprio(1);
      MFMA_Z(accm[0][0], p0, areg[0][0]); MFMA_Z(accm[0][1], p0, areg[1][0]);
      MFMA_Z(accm[0][2], p0, areg[2][0]); MFMA_Z(accm[0][3], p0, areg[3][0]);
      MFMA_Z(accm[1][0], p1, areg[0][0]); MFMA_Z(accm[1][1], p1, areg[1][0]);
      MFMA_Z(accm[1][2], p1, areg[2][0]); MFMA_Z(accm[1][3], p1, areg[3][0]);
      __builtin_amdgcn_s_setprio(0);
    }
    // ---- ks1: 2 frag reads + 8 MFMA (accumulate)
    {
      s16x8 p0 = *(const s16x8*)(bbase + (offX ^ 64));
      s16x8 p1 = *(const s16x8*)(bbase + ((offX + 2048) ^ 64));
      __builtin_amdgcn_s_setprio(1);
      MFMA_ACC(accm[0][0], p0, areg[0][1]); MFMA_ACC(accm[0][1], p0, areg[1][1]);
      MFMA_ACC(accm[0][2], p0, areg[2][1]); MFMA_ACC(accm[0][3], p0, areg[3][1]);
      MFMA_ACC(accm[1][0], p1, areg[0][1]); MFMA_ACC(accm[1][1], p1, areg[1][1]);
      MFMA_ACC(accm[1][2], p1, areg[2][1]); MFMA_ACC(accm[1][3], p1, areg[3][1]);
      __builtin_amdgcn_s_setprio(0);
    }
    // ---- z-frag prefetch for next d-chunk (A buffer landed at m==14's drain)
    if (m == 15 && dc < 7) {
      const char* abase = smem + ((dc + 1) & 1) * 16384;
      #pragma unroll
      for (int j = 0; j < 4; ++j) {
        areg[j][0] = *(const s16x8*)(abase + (offY + j * 2048));
        areg[j][1] = *(const s16x8*)(abase + ((offY + j * 2048) ^ 64));
      }
    }
    // ---- gated fold (packed f32): g per b-frag j
    #pragma unroll
    for (int i = 0; i < 2; ++i) {
      f32x2 ga = {g0, g0}, gb = {g1, g1}, gc = {g2, g2}, gd = {g3, g3};
      f32x2* a0 = (f32x2*)&acc[i][0];
      f32x2* a1 = (f32x2*)&acc[i][1];
      f32x2* a2 = (f32x2*)&acc[i][2];
      f32x2* a3 = (f32x2*)&acc[i][3];
      const f32x2* m0p = (const f32x2*)&accm[i][0];
      const f32x2* m1p = (const f32x2*)&accm[i][1];
      const f32x2* m2p = (const f32x2*)&accm[i][2];
      const f32x2* m3p = (const f32x2*)&accm[i][3];
      a0[0] += ga * m0p[0]; a0[1] += ga * m0p[1];
      a1[0] += gb * m1p[0]; a1[1] += gb * m1p[1];
      a2[0] += gc * m2p[0]; a2[1] += gc * m2p[1];
      a3[0] += gd * m3p[0]; a3[1] += gd * m3p[1];
    }

    asm volatile("s_waitcnt vmcnt(0)" ::: "memory");  // next tile landed
    __builtin_amdgcn_s_barrier();
  }

  // ---- epilogue: acc[i][j][jj] -> dzT[e][b];  e-row = (lane>>4)*4+jj contig
  #pragma unroll
  for (int i = 0; i < 2; ++i) {
    int e = bcol * 128 + wc * 32 + i * 16 + ((lane >> 4) << 2);
    #pragma unroll
    for (int j = 0; j < 4; ++j) {
      size_t b = (size_t)brow * 128 + wr * 64 + j * 16 + lrow;
      *(f32x4*)(dz + b * D_N + e) = acc[i][j];
    }
  }
}

// ---------------------------------------------------------------------------
extern "C" void kernel_launch(void* const* d_in, const int* in_sizes, int n_in,
                              void* d_out, int out_size, void* d_ws, size_t ws_size,
                              hipStream_t stream) {
  const float* z   = (const float*)d_in[1];
  const float* Psi = (const float*)d_in[2];
  const float* gt  = (const float*)d_in[3];
  float* dz = (float*)d_out;

  // ws: wT 32KB | gatesb 512KB | Psib 8MB | zb16 16MB  (~24.5MB)
  float* wT = (float*)d_ws;
  unsigned short* gatesb = (unsigned short*)((char*)d_ws + 32768);
  short* Psib = (short*)((char*)d_ws + 32768 + 524288);
  short* zb16 = Psib + (size_t)M_N * D_N * D_N;

  k_trw <<<dim3(8, M_N), dim3(256), 0, stream>>>(Psi, gt, Psib, wT);
  k_gz  <<<dim3(B_N / 16), dim3(256), 0, stream>>>(z, wT, zb16, gatesb);
  k_gemm<<<dim3(512), dim3(512), 0, stream>>>((const char*)zb16, gatesb,
                                              (const char*)Psib, dz);
}

// Round 13
// 170.631 us; speedup vs baseline: 1.1006x; 1.0489x over previous
//
#include <hip/hip_runtime.h>
#include <hip/hip_bf16.h>

#define B_N 16384
#define D_N 512
#define M_N 16

typedef __attribute__((ext_vector_type(4))) float  f32x4;
typedef __attribute__((ext_vector_type(2))) float  f32x2;
typedef __attribute__((ext_vector_type(8))) short  s16x8;
typedef __attribute__((ext_vector_type(4))) unsigned short u16x4;

__device__ __forceinline__ short bf16_of(float f) {
  union { float f; unsigned u; } v; v.f = f;
  unsigned r = v.u + 0x7fffu + ((v.u >> 16) & 1u);  // RNE
  return (short)(r >> 16);
}
__device__ __forceinline__ float f32_of_bf16(unsigned short u) {
  union { unsigned u; float f; } v; v.u = ((unsigned)u) << 16; return v.f;
}
__device__ __forceinline__ void gload_lds16(const void* g, void* l) {
  __builtin_amdgcn_global_load_lds(
      (const __attribute__((address_space(1))) unsigned*)g,
      (__attribute__((address_space(3))) unsigned*)l, 16, 0, 0);
}

#define MFMA_ACC(d, x, y) d = __builtin_amdgcn_mfma_f32_16x16x32_bf16(x, y, d, 0, 0, 0)
#define MFMA_Z(d, x, y)   d = __builtin_amdgcn_mfma_f32_16x16x32_bf16(x, y, FZERO, 0, 0, 0)

// ---------------------------------------------------------------------------
// Kernel 1 (fused): Psib[m][e][d] = bf16(Psi[m][d][e]) pre-swizzled, AND
// wT[d,m] = sum_e Psi[m,d,e]*gt[m,e] (f32 exact path for gates).
// ---------------------------------------------------------------------------
__global__ void k_trw(const float* __restrict__ Psi, const float* __restrict__ gt,
                      short* __restrict__ Psib, float* __restrict__ wT) {
  int m = blockIdx.y, d0 = blockIdx.x << 6;
  __shared__ float tile[64][65];
  __shared__ float gs[D_N];
  int t = threadIdx.x;
  for (int i = t; i < D_N; i += 256) gs[i] = gt[m * D_N + i];
  int r = t >> 2, q = t & 3;
  float wacc = 0.f;
  const float* src = Psi + (size_t)m * D_N * D_N;
  short* dst = Psib + (size_t)m * D_N * D_N;
  for (int e0 = 0; e0 < D_N; e0 += 64) {
    __syncthreads();
    #pragma unroll
    for (int j = 0; j < 4; ++j) {
      int idx = t + (j << 8);
      int rr = idx >> 4, c4 = idx & 15;
      *(f32x4*)&tile[rr][c4 * 4] = *(const f32x4*)(src + (size_t)(d0 + rr) * D_N + e0 + c4 * 4);
    }
    __syncthreads();
    #pragma unroll
    for (int k = 0; k < 16; ++k) wacc += tile[r][q * 16 + k] * gs[e0 + q * 16 + k];
    #pragma unroll
    for (int it = 0; it < 2; ++it) {
      int idx = t + (it << 8);
      int el = idx >> 3, jb = idx & 7;
      int e = e0 + el;
      s16x8 o;
      #pragma unroll
      for (int k = 0; k < 8; ++k) o[k] = bf16_of(tile[jb * 8 + k][el]);
      int db = jb ^ (e & 7);
      *(s16x8*)(dst + (size_t)e * D_N + d0 + db * 8) = o;
    }
  }
  wacc += __shfl_xor(wacc, 1);
  wacc += __shfl_xor(wacc, 2);
  if (q == 0) wT[(d0 + r) * M_N + m] = wacc;
}

// ---------------------------------------------------------------------------
// Kernel 2 (fused): gates (bf16) + pre-swizzled bf16 z, one z read.
// ---------------------------------------------------------------------------
__global__ void k_gz(const float* __restrict__ z, const float* __restrict__ wT,
                     short* __restrict__ zb, unsigned short* __restrict__ gatesb) {
  __shared__ float zs[16][D_N];
  int t = threadIdx.x;
  size_t b0 = (size_t)blockIdx.x * 16;
  #pragma unroll
  for (int j = 0; j < 8; ++j) {
    int idx = t + (j << 8);
    int r = idx >> 7, c4 = idx & 127;
    *(f32x4*)&zs[r][c4 * 4] = *(const f32x4*)(z + (b0 + r) * D_N + c4 * 4);
  }
  __syncthreads();
  int r = t >> 4, m = t & 15;
  float s0 = 0.f, s1 = 0.f, s2 = 0.f, s3 = 0.f;
  #pragma unroll 4
  for (int e = 0; e < D_N; e += 4) {
    s0 += zs[r][e + 0] * wT[(e + 0) * M_N + m];
    s1 += zs[r][e + 1] * wT[(e + 1) * M_N + m];
    s2 += zs[r][e + 2] * wT[(e + 2) * M_N + m];
    s3 += zs[r][e + 3] * wT[(e + 3) * M_N + m];
  }
  float s = (s0 + s1) + (s2 + s3);
  float sig = 1.f / (1.f + expf(-s));
  gatesb[(b0 + r) * M_N + m] = (unsigned short)bf16_of(fmaxf(2.f * sig - 1.f, 0.f));
  #pragma unroll
  for (int j = 0; j < 4; ++j) {
    int idx = t + (j << 8);
    int rr = idx >> 6, blk = idx & 63;
    int chunk = blk >> 3, ib = blk & 7;
    int sb = ib ^ (rr & 7);
    const float* sp = &zs[rr][chunk * 64 + sb * 8];
    s16x8 o;
    #pragma unroll
    for (int k = 0; k < 8; ++k) o[k] = bf16_of(sp[k]);
    *(s16x8*)(zb + (b0 + rr) * D_N + blk * 8) = o;
  }
}

// ---------------------------------------------------------------------------
// Kernel 3: GEMM dz^T = sum_m g_m*(Psi_m^T @ z^T).  Round 13 = round 10 with
// counted vmcnt (T4): NBUF=3 B buffers + single A buffer, uniform vmcnt(2)
// at step end (2 B-loads always in flight across barriers; NEVER drain to 0
// mid-loop), vmcnt(4) when A also in flight.  Everything else identical to
// round 10: 16x16x32 MFMA, 4b x 2e wave grid, 8 independent accm chains,
// 2 blocks/CU, A-centric XCD map.
// LDS 72KB: A 16KB @0 | B 3x16KB @16384 | gates f32 8KB @65536.
// ---------------------------------------------------------------------------
__global__ __launch_bounds__(512, 4) void k_gemm(
    const char* __restrict__ zb, const unsigned short* __restrict__ gatesb,
    const char* __restrict__ pb, float* __restrict__ dz) {
  __shared__ __align__(128) char smem[73728];
  float* glf = (float*)(smem + 65536);

  const int tid = threadIdx.x;
  const int lane = tid & 63;
  const int wid = tid >> 6;            // 0..7
  const int wr = wid >> 1;             // b-group: 4 x 32 rows
  const int wc = wid & 1;              // e-group: 2 x 64 cols
  const int bid = blockIdx.x;          // 512 blocks
  const int xcd = bid & 7;
  const int g8 = bid >> 3;             // 0..63
  const int bcol = g8 & 3;
  const int brow = xcd * 16 + (g8 >> 2);  // 16 brow-slabs/XCD -> 2MB z, L2-fit

  // ---- gates -> LDS [m][128 rows] f32
  {
    int row = tid >> 2, g4 = tid & 3;
    u16x4 gv = *(const u16x4*)(gatesb + ((size_t)(brow * 128 + row) << 4) + (g4 << 2));
    #pragma unroll
    for (int k = 0; k < 4; ++k)
      glf[(g4 * 4 + k) * 128 + row] = f32_of_bf16(gv[k]);
  }

  const int rsub = lane >> 3, cbyte = (lane & 7) << 4;

  auto stageA = [&](int dc) {             // 2 loads into the single A buffer
    #pragma unroll
    for (int j = 0; j < 2; ++j) {
      const char* g = zb + (((size_t)(brow * 128 + wid * 8 + j * 64 + rsub)) << 10)
                      + (dc << 7) + cbyte;
      gload_lds16(g, smem + (wid << 10) + (j << 13));
    }
  };
  auto stageB = [&](int m, int dc, int qb) {  // 2 loads: 128 e-rows x 128B
    #pragma unroll
    for (int j = 0; j < 2; ++j) {
      const char* g = pb + (((size_t)(m * 512 + bcol * 128 + wid * 8 + j * 64 + rsub)) << 10)
                      + (dc << 7) + cbyte;
      gload_lds16(g, smem + 16384 + (qb << 14) + (wid << 10) + (j << 13));
    }
  };

  const int lrow = lane & 15;
  const int kq16 = (((lane >> 4) << 4)) ^ ((lrow & 7) << 4);
  const int offY = ((wr * 32 + lrow) << 7) + kq16;   // z frags (y operand)
  const int offX = ((wc * 64 + lrow) << 7) + kq16;   // Psi frags (x operand)
  const int grow = wr * 32 + lrow;                   // gate row base

  f32x4 acc[4][2] = {};
  f32x4 accm[4][2];
  s16x8 areg[2][2];
  const f32x4 FZERO = {0.f, 0.f, 0.f, 0.f};

  // ---- prologue: A(dc0), B(s=0), B(s=1); drain; barrier
  stageA(0);
  stageB(0, 0, 0);
  stageB(1, 0, 1);
  asm volatile("s_waitcnt vmcnt(0) lgkmcnt(0)" ::: "memory");
  __builtin_amdgcn_s_barrier();

  int q = 0;                                // B buffer for current step
  #pragma unroll 1
  for (int s = 0; s < 128; ++s) {
    const int m = s & 15, dc = s >> 4;
    int q2 = q + 2; if (q2 >= 3) q2 -= 3;

    // ---- issue stages first: B(s+2), and A(dc+1) at m==14
    if (s + 2 < 128) stageB((s + 2) & 15, (s + 2) >> 4, q2);
    const bool aw = (m == 14) && (dc < 7);
    if (aw) stageA(dc + 1);

    // ---- z frags once per d-chunk (A landed: guaranteed by m15's vmcnt(2))
    if (m == 0) {
      #pragma unroll
      for (int j = 0; j < 2; ++j) {
        areg[j][0] = *(const s16x8*)(smem + (offY + j * 2048));
        areg[j][1] = *(const s16x8*)(smem + ((offY + j * 2048) ^ 64));
      }
    }
    float g0 = glf[(m << 7) + grow];
    float g1 = glf[(m << 7) + grow + 16];

    const char* bbase = smem + 16384 + (q << 14);
    // ---- ks0: 4 frag reads + 8 MFMA (C=0, 8 independent chains)
    {
      s16x8 p0 = *(const s16x8*)(bbase + (offX));
      s16x8 p1 = *(const s16x8*)(bbase + (offX + 2048));
      s16x8 p2 = *(const s16x8*)(bbase + (offX + 4096));
      s16x8 p3 = *(const s16x8*)(bbase + (offX + 6144));
      __builtin_amdgcn_s_setprio(1);
      MFMA_Z(accm[0][0], p0, areg[0][0]); MFMA_Z(accm[0][1], p0, areg[1][0]);
      MFMA_Z(accm[1][0], p1, areg[0][0]); MFMA_Z(accm[1][1], p1, areg[1][0]);
      MFMA_Z(accm[2][0], p2, areg[0][0]); MFMA_Z(accm[2][1], p2, areg[1][0]);
      MFMA_Z(accm[3][0], p3, areg[0][0]); MFMA_Z(accm[3][1], p3, areg[1][0]);
      __builtin_amdgcn_s_setprio(0);
    }
    // ---- ks1: 4 frag reads + 8 MFMA (accumulate)
    {
      s16x8 p0 = *(const s16x8*)(bbase + (offX ^ 64));
      s16x8 p1 = *(const s16x8*)(bbase + ((offX + 2048) ^ 64));
      s16x8 p2 = *(const s16x8*)(bbase + ((offX + 4096) ^ 64));
      s16x8 p3 = *(const s16x8*)(bbase + ((offX + 6144) ^ 64));
      __builtin_amdgcn_s_setprio(1);
      MFMA_ACC(accm[0][0], p0, areg[0][1]); MFMA_ACC(accm[0][1], p0, areg[1][1]);
      MFMA_ACC(accm[1][0], p1, areg[0][1]); MFMA_ACC(accm[1][1], p1, areg[1][1]);
      MFMA_ACC(accm[2][0], p2, areg[0][1]); MFMA_ACC(accm[2][1], p2, areg[1][1]);
      MFMA_ACC(accm[3][0], p3, areg[0][1]); MFMA_ACC(accm[3][1], p3, areg[1][1]);
      __builtin_amdgcn_s_setprio(0);
    }
    // ---- gated fold (packed f32)
    #pragma unroll
    for (int i = 0; i < 4; ++i) {
      f32x2 ga = {g0, g0}, gb = {g1, g1};
      f32x2* a0 = (f32x2*)&acc[i][0];
      f32x2* a1 = (f32x2*)&acc[i][1];
      const f32x2* m0p = (const f32x2*)&accm[i][0];
      const f32x2* m1p = (const f32x2*)&accm[i][1];
      a0[0] += ga * m0p[0]; a0[1] += ga * m0p[1];
      a1[0] += gb * m1p[0]; a1[1] += gb * m1p[1];
    }

    // ---- counted wait: keep B(s+2) (and A) in flight; never drain mid-loop
    if (aw)
      asm volatile("s_waitcnt vmcnt(4)" ::: "memory");  // B(s+1) landed; A+B(s+2) fly
    else if (s >= 126)
      asm volatile("s_waitcnt vmcnt(0)" ::: "memory");  // tail drain
    else
      asm volatile("s_waitcnt vmcnt(2)" ::: "memory");  // B(s+1) landed; B(s+2) flies
    if (s < 127) __builtin_amdgcn_s_barrier();
    q = (q + 1 == 3) ? 0 : q + 1;
  }

  // ---- epilogue: acc[i][j][jj] = dzT[e][b]
  #pragma unroll
  for (int i = 0; i < 4; ++i) {
    int e = bcol * 128 + wc * 64 + i * 16 + ((lane >> 4) << 2);
    #pragma unroll
    for (int j = 0; j < 2; ++j) {
      size_t b = (size_t)brow * 128 + wr * 32 + j * 16 + lrow;
      *(f32x4*)(dz + b * D_N + e) = acc[i][j];
    }
  }
}

// ---------------------------------------------------------------------------
extern "C" void kernel_launch(void* const* d_in, const int* in_sizes, int n_in,
                              void* d_out, int out_size, void* d_ws, size_t ws_size,
                              hipStream_t stream) {
  const float* z   = (const float*)d_in[1];
  const float* Psi = (const float*)d_in[2];
  const float* gt  = (const float*)d_in[3];
  float* dz = (float*)d_out;

  // ws: wT 32KB | gatesb 512KB | Psib 8MB | zb16 16MB  (~24.5MB)
  float* wT = (float*)d_ws;
  unsigned short* gatesb = (unsigned short*)((char*)d_ws + 32768);
  short* Psib = (short*)((char*)d_ws + 32768 + 524288);
  short* zb16 = Psib + (size_t)M_N * D_N * D_N;

  k_trw <<<dim3(8, M_N), dim3(256), 0, stream>>>(Psi, gt, Psib, wT);
  k_gz  <<<dim3(B_N / 16), dim3(256), 0, stream>>>(z, wT, zb16, gatesb);
  k_gemm<<<dim3(512), dim3(512), 0, stream>>>((const char*)zb16, gatesb,
                                              (const char*)Psib, dz);
}

// Round 14
// 160.554 us; speedup vs baseline: 1.1697x; 1.0628x over previous
//
#include <hip/hip_runtime.h>
#include <hip/hip_bf16.h>

#define B_N 16384
#define D_N 512
#define M_N 16

typedef __attribute__((ext_vector_type(4))) float  f32x4;
typedef __attribute__((ext_vector_type(8))) short  s16x8;

__device__ __forceinline__ short bf16_of(float f) {
  union { float f; unsigned u; } v; v.f = f;
  unsigned r = v.u + 0x7fffu + ((v.u >> 16) & 1u);  // RNE
  return (short)(r >> 16);
}
__device__ __forceinline__ float f32_of_bf16(unsigned short u) {
  union { unsigned u; float f; } v; v.u = ((unsigned)u) << 16; return v.f;
}
__device__ __forceinline__ void gload_lds16(const void* g, void* l) {
  __builtin_amdgcn_global_load_lds(
      (const __attribute__((address_space(1))) unsigned*)g,
      (__attribute__((address_space(3))) unsigned*)l, 16, 0, 0);
}

#define MFMA_ACC(d, x, y) d = __builtin_amdgcn_mfma_f32_16x16x32_bf16(x, y, d, 0, 0, 0)
#define MFMA_Z(d, x, y)   d = __builtin_amdgcn_mfma_f32_16x16x32_bf16(x, y, FZERO, 0, 0, 0)

// ---------------------------------------------------------------------------
// Kernel 1 (fused): Psib[m][e][d] = bf16(Psi[m][d][e]) pre-swizzled, AND
// wT[d,m] = sum_e Psi[m,d,e]*gt[m,e] (f32 exact path for gates).
// ---------------------------------------------------------------------------
__global__ void k_trw(const float* __restrict__ Psi, const float* __restrict__ gt,
                      short* __restrict__ Psib, float* __restrict__ wT) {
  int m = blockIdx.y, d0 = blockIdx.x << 6;
  __shared__ float tile[64][65];
  __shared__ float gs[D_N];
  int t = threadIdx.x;
  for (int i = t; i < D_N; i += 256) gs[i] = gt[m * D_N + i];
  int r = t >> 2, q = t & 3;
  float wacc = 0.f;
  const float* src = Psi + (size_t)m * D_N * D_N;
  short* dst = Psib + (size_t)m * D_N * D_N;
  for (int e0 = 0; e0 < D_N; e0 += 64) {
    __syncthreads();
    #pragma unroll
    for (int j = 0; j < 4; ++j) {
      int idx = t + (j << 8);
      int rr = idx >> 4, c4 = idx & 15;
      *(f32x4*)&tile[rr][c4 * 4] = *(const f32x4*)(src + (size_t)(d0 + rr) * D_N + e0 + c4 * 4);
    }
    __syncthreads();
    #pragma unroll
    for (int k = 0; k < 16; ++k) wacc += tile[r][q * 16 + k] * gs[e0 + q * 16 + k];
    #pragma unroll
    for (int it = 0; it < 2; ++it) {
      int idx = t + (it << 8);
      int el = idx >> 3, jb = idx & 7;
      int e = e0 + el;
      s16x8 o;
      #pragma unroll
      for (int k = 0; k < 8; ++k) o[k] = bf16_of(tile[jb * 8 + k][el]);
      int db = jb ^ (e & 7);
      *(s16x8*)(dst + (size_t)e * D_N + d0 + db * 8) = o;
    }
  }
  wacc += __shfl_xor(wacc, 1);
  wacc += __shfl_xor(wacc, 2);
  if (q == 0) wT[(d0 + r) * M_N + m] = wacc;
}

// ---------------------------------------------------------------------------
// Kernel 2 (fused): gates (bf16) + pre-swizzled bf16 z, one z read.
// ---------------------------------------------------------------------------
__global__ void k_gz(const float* __restrict__ z, const float* __restrict__ wT,
                     short* __restrict__ zb, unsigned short* __restrict__ gatesb) {
  __shared__ float zs[16][D_N];
  int t = threadIdx.x;
  size_t b0 = (size_t)blockIdx.x * 16;
  #pragma unroll
  for (int j = 0; j < 8; ++j) {
    int idx = t + (j << 8);
    int r = idx >> 7, c4 = idx & 127;
    *(f32x4*)&zs[r][c4 * 4] = *(const f32x4*)(z + (b0 + r) * D_N + c4 * 4);
  }
  __syncthreads();
  int r = t >> 4, m = t & 15;
  float s0 = 0.f, s1 = 0.f, s2 = 0.f, s3 = 0.f;
  #pragma unroll 4
  for (int e = 0; e < D_N; e += 4) {
    s0 += zs[r][e + 0] * wT[(e + 0) * M_N + m];
    s1 += zs[r][e + 1] * wT[(e + 1) * M_N + m];
    s2 += zs[r][e + 2] * wT[(e + 2) * M_N + m];
    s3 += zs[r][e + 3] * wT[(e + 3) * M_N + m];
  }
  float s = (s0 + s1) + (s2 + s3);
  float sig = 1.f / (1.f + expf(-s));
  gatesb[(b0 + r) * M_N + m] = (unsigned short)bf16_of(fmaxf(2.f * sig - 1.f, 0.f));
  #pragma unroll
  for (int j = 0; j < 4; ++j) {
    int idx = t + (j << 8);
    int rr = idx >> 6, blk = idx & 63;
    int chunk = blk >> 3, ib = blk & 7;
    int sb = ib ^ (rr & 7);
    const float* sp = &zs[rr][chunk * 64 + sb * 8];
    s16x8 o;
    #pragma unroll
    for (int k = 0; k < 8; ++k) o[k] = bf16_of(sp[k]);
    *(s16x8*)(zb + (b0 + rr) * D_N + blk * 8) = o;
  }
}

// ---------------------------------------------------------------------------
// Kernel 3: GEMM dz^T-tiles = sum_m g_m * (Psi_m^T @ z^T).  256(b)x128(e)
// block, 8 waves, d-OUTER / m-INNER (z frags reg-cached per d-chunk);
// Psi-side fragments pipelined in regs (bx/by ping-pong); ONE barrier per
// step; NBUF=4 B-buffers, counted vmcnt; first-MFMA C=0; gate prefetch one
// step ahead; gates held as f32 in LDS.   [R7 configuration — session best]
// ---------------------------------------------------------------------------
__global__ __launch_bounds__(512, 2) void k_gemm(
    const char* __restrict__ zb, const unsigned short* __restrict__ gatesb,
    const char* __restrict__ pb, float* __restrict__ dz) {
  // A bufs 2x32KB @0 | B bufs 4x16KB @65536 | gates f32 16KB @131072
  __shared__ __align__(128) char smem[147456];
  float* glf = (float*)(smem + 131072);

  const int tid = threadIdx.x;
  const int lane = tid & 63;
  const int wid = tid >> 6;
  const int wr = wid >> 1;             // b-block (64 rows of 256)
  const int wc = wid & 1;              // e-block (64 cols of 128)
  const int bid = blockIdx.x;
  const int xcd = bid & 7;
  const int g8 = bid >> 3;
  const int bcol = g8 & 3;
  const int brow = xcd * 8 + (g8 >> 2);  // A-centric XCD map (L2-resident z)

  // ---- gates -> LDS [m][256 rows] f32 (converted once here)
  {
    s16x8 gv = *(const s16x8*)(gatesb + ((size_t)brow << 12) + ((size_t)tid << 3));
    int row = tid >> 1, mbase = (tid & 1) << 3;
    #pragma unroll
    for (int k = 0; k < 8; ++k)
      glf[(mbase + k) * 256 + row] = f32_of_bf16((unsigned short)gv[k]);
  }

  const int rsub = lane >> 3, cbyte = (lane & 7) << 4;

  auto stageA = [&](int ab, int dc) {     // 4 loads: 256 rows x 128B d-chunk
    #pragma unroll
    for (int j = 0; j < 4; ++j) {
      const char* g = zb + (((size_t)(brow * 256 + wid * 8 + j * 64 + rsub)) << 10)
                      + (dc << 7) + cbyte;
      gload_lds16(g, smem + ab * 32768 + (wid << 10) + (j << 13));
    }
  };
  auto stageB = [&](int m, int dc, int q) {  // 2 loads: 128 e-rows x 128B
    #pragma unroll
    for (int j = 0; j < 2; ++j) {
      const char* g = pb + (((size_t)(m * 512 + bcol * 128 + wid * 8 + j * 64 + rsub)) << 10)
                      + (dc << 7) + cbyte;
      gload_lds16(g, smem + 65536 + q * 16384 + (wid << 10) + (j << 13));
    }
  };

  const int lrow = lane & 15;
  const int swz = (lrow & 7) << 4;
  const int kq16 = (((lane >> 4) << 4)) ^ swz;
  const int offY = ((wr * 64 + lrow) << 7) + kq16;   // z frags (y operand)
  const int offX = ((wc * 64 + lrow) << 7) + kq16;   // Psi frags (x operand)
  const int grow = wr * 64 + lrow;                   // gate row base

  f32x4 acc[4][4] = {};
  f32x4 accm[4][4];
  s16x8 areg[4][2];
  s16x8 bx[4], by[4];
  float gjc[4], gjn[4];
  const f32x4 FZERO = {0.f, 0.f, 0.f, 0.f};

  // ---- prologue: A(dc0), B(0..2); drain; preload bx + gates for s=0
  stageA(0, 0);
  stageB(0, 0, 0); stageB(1, 0, 1); stageB(2, 0, 2);
  asm volatile("s_waitcnt vmcnt(0) lgkmcnt(0)" ::: "memory");
  __builtin_amdgcn_s_barrier();
  #pragma unroll
  for (int i = 0; i < 4; ++i)
    bx[i] = *(const s16x8*)(smem + 65536 + (offX + i * 2048));
  #pragma unroll
  for (int j = 0; j < 4; ++j)
    gjc[j] = glf[grow + j * 16];   // m=0

  #pragma unroll 1
  for (int s = 0; s < 128; ++s) {
    const int m = s & 15, dc = s >> 4;
    const char* bbase_cur = smem + 65536 + (s & 3) * 16384;
    const char* bbase_nxt = smem + 65536 + ((s + 1) & 3) * 16384;

    // ---- reads for this step (z frags at dc start, ks1 Psi frags, next gates)
    if (m == 0) {
      const char* abase = smem + (dc & 1) * 32768;
      #pragma unroll
      for (int j = 0; j < 4; ++j) {
        areg[j][0] = *(const s16x8*)(abase + (offY + j * 2048));
        areg[j][1] = *(const s16x8*)(abase + ((offY + j * 2048) ^ 64));
      }
    }
    #pragma unroll
    for (int i = 0; i < 4; ++i)
      by[i] = *(const s16x8*)(bbase_cur + ((offX + i * 2048) ^ 64));
    {
      const int mn = (s + 1) & 15;
      #pragma unroll
      for (int j = 0; j < 4; ++j)
        gjn[j] = glf[mn * 256 + grow + j * 16];
    }
    if (s + 3 < 128) stageB((s + 3) & 15, (s + 3) >> 4, (s + 3) & 3);
    if (m == 11 && dc < 7) stageA((dc & 1) ^ 1, dc + 1);

    // ---- section A: 16 MFMA, C = 0 (kills accm zeroing)
    __builtin_amdgcn_s_setprio(1);
    #pragma unroll
    for (int i = 0; i < 4; ++i)
      #pragma unroll
      for (int j = 0; j < 4; ++j)
        MFMA_Z(accm[i][j], bx[i], areg[j][0]);
    __builtin_amdgcn_s_setprio(0);

    // ---- read next step's ks0 Psi frags (hidden under section-B MFMAs)
    if (s < 127) {
      #pragma unroll
      for (int i = 0; i < 4; ++i)
        bx[i] = *(const s16x8*)(bbase_nxt + (offX + i * 2048));
    }

    // ---- section B: 16 MFMA accumulate, then gated fold
    __builtin_amdgcn_s_setprio(1);
    #pragma unroll
    for (int i = 0; i < 4; ++i)
      #pragma unroll
      for (int j = 0; j < 4; ++j)
        MFMA_ACC(accm[i][j], by[i], areg[j][1]);
    __builtin_amdgcn_s_setprio(0);
    #pragma unroll
    for (int i = 0; i < 4; ++i)
      #pragma unroll
      for (int j = 0; j < 4; ++j)
        #pragma unroll
        for (int jj = 0; jj < 4; ++jj)
          acc[i][j][jj] = fmaf(gjc[j], accm[i][j][jj], acc[i][j][jj]);
    #pragma unroll
    for (int j = 0; j < 4; ++j) gjc[j] = gjn[j];

    if (dc < 7 && (m == 11 || m == 12))
      asm volatile("s_waitcnt vmcnt(6)" ::: "memory");   // A(dc+1)+2 B-tiles in flight
    else if (s >= 125)
      asm volatile("s_waitcnt vmcnt(0)" ::: "memory");   // epilogue drain
    else
      asm volatile("s_waitcnt vmcnt(2)" ::: "memory");   // B(s+2) landed, B(s+3) in flight
    __builtin_amdgcn_s_barrier();
  }

  // ---- epilogue: acc[i][j][jj] = dzT[e][b]
  #pragma unroll
  for (int i = 0; i < 4; ++i) {
    int e = bcol * 128 + wc * 64 + i * 16 + ((lane >> 4) << 2);
    #pragma unroll
    for (int j = 0; j < 4; ++j) {
      size_t b = (size_t)brow * 256 + wr * 64 + j * 16 + lrow;
      *(f32x4*)(dz + b * D_N + e) = acc[i][j];
    }
  }
}

// ---------------------------------------------------------------------------
extern "C" void kernel_launch(void* const* d_in, const int* in_sizes, int n_in,
                              void* d_out, int out_size, void* d_ws, size_t ws_size,
                              hipStream_t stream) {
  const float* z   = (const float*)d_in[1];
  const float* Psi = (const float*)d_in[2];
  const float* gt  = (const float*)d_in[3];
  float* dz = (float*)d_out;

  // ws: wT 32KB | gatesb 512KB | Psib 8MB | zb16 16MB  (~24.5MB)
  float* wT = (float*)d_ws;
  unsigned short* gatesb = (unsigned short*)((char*)d_ws + 32768);
  short* Psib = (short*)((char*)d_ws + 32768 + 524288);
  short* zb16 = Psib + (size_t)M_N * D_N * D_N;

  k_trw <<<dim3(8, M_N), dim3(256), 0, stream>>>(Psi, gt, Psib, wT);
  k_gz  <<<dim3(B_N / 16), dim3(256), 0, stream>>>(z, wT, zb16, gatesb);
  k_gemm<<<dim3(256), dim3(512), 0, stream>>>((const char*)zb16, gatesb,
                                              (const char*)Psib, dz);
}

// Round 15
// 155.079 us; speedup vs baseline: 1.2109x; 1.0353x over previous
//
#include <hip/hip_runtime.h>
#include <hip/hip_bf16.h>

#define B_N 16384
#define D_N 512
#define M_N 16

typedef __attribute__((ext_vector_type(4))) float  f32x4;
typedef __attribute__((ext_vector_type(8))) short  s16x8;

__device__ __forceinline__ short bf16_of(float f) {
  union { float f; unsigned u; } v; v.f = f;
  unsigned r = v.u + 0x7fffu + ((v.u >> 16) & 1u);  // RNE
  return (short)(r >> 16);
}
__device__ __forceinline__ float f32_of_bf16(unsigned short u) {
  union { unsigned u; float f; } v; v.u = ((unsigned)u) << 16; return v.f;
}
__device__ __forceinline__ void gload_lds16(const void* g, void* l) {
  __builtin_amdgcn_global_load_lds(
      (const __attribute__((address_space(1))) unsigned*)g,
      (__attribute__((address_space(3))) unsigned*)l, 16, 0, 0);
}

#define MFMA_ACC(d, x, y) d = __builtin_amdgcn_mfma_f32_16x16x32_bf16(x, y, d, 0, 0, 0)
#define MFMA_Z(d, x, y)   d = __builtin_amdgcn_mfma_f32_16x16x32_bf16(x, y, FZERO, 0, 0, 0)

// ---------------------------------------------------------------------------
// Kernel 1 (fused): Psib[m][e][d] = bf16(Psi[m][d][e]) pre-swizzled, AND
// wT[d,m] = sum_e Psi[m,d,e]*gt[m,e] (f32 exact path for gates).
// ---------------------------------------------------------------------------
__global__ void k_trw(const float* __restrict__ Psi, const float* __restrict__ gt,
                      short* __restrict__ Psib, float* __restrict__ wT) {
  int m = blockIdx.y, d0 = blockIdx.x << 6;
  __shared__ float tile[64][65];
  __shared__ float gs[D_N];
  int t = threadIdx.x;
  for (int i = t; i < D_N; i += 256) gs[i] = gt[m * D_N + i];
  int r = t >> 2, q = t & 3;
  float wacc = 0.f;
  const float* src = Psi + (size_t)m * D_N * D_N;
  short* dst = Psib + (size_t)m * D_N * D_N;
  for (int e0 = 0; e0 < D_N; e0 += 64) {
    __syncthreads();
    #pragma unroll
    for (int j = 0; j < 4; ++j) {
      int idx = t + (j << 8);
      int rr = idx >> 4, c4 = idx & 15;
      *(f32x4*)&tile[rr][c4 * 4] = *(const f32x4*)(src + (size_t)(d0 + rr) * D_N + e0 + c4 * 4);
    }
    __syncthreads();
    #pragma unroll
    for (int k = 0; k < 16; ++k) wacc += tile[r][q * 16 + k] * gs[e0 + q * 16 + k];
    #pragma unroll
    for (int it = 0; it < 2; ++it) {
      int idx = t + (it << 8);
      int el = idx >> 3, jb = idx & 7;
      int e = e0 + el;
      s16x8 o;
      #pragma unroll
      for (int k = 0; k < 8; ++k) o[k] = bf16_of(tile[jb * 8 + k][el]);
      int db = jb ^ (e & 7);
      *(s16x8*)(dst + (size_t)e * D_N + d0 + db * 8) = o;
    }
  }
  wacc += __shfl_xor(wacc, 1);
  wacc += __shfl_xor(wacc, 2);
  if (q == 0) wT[(d0 + r) * M_N + m] = wacc;
}

// ---------------------------------------------------------------------------
// Kernel 2 (fused): gates (bf16) + pre-swizzled bf16 z, one z read.
// ---------------------------------------------------------------------------
__global__ void k_gz(const float* __restrict__ z, const float* __restrict__ wT,
                     short* __restrict__ zb, unsigned short* __restrict__ gatesb) {
  __shared__ float zs[16][D_N];
  int t = threadIdx.x;
  size_t b0 = (size_t)blockIdx.x * 16;
  #pragma unroll
  for (int j = 0; j < 8; ++j) {
    int idx = t + (j << 8);
    int r = idx >> 7, c4 = idx & 127;
    *(f32x4*)&zs[r][c4 * 4] = *(const f32x4*)(z + (b0 + r) * D_N + c4 * 4);
  }
  __syncthreads();
  int r = t >> 4, m = t & 15;
  float s0 = 0.f, s1 = 0.f, s2 = 0.f, s3 = 0.f;
  #pragma unroll 4
  for (int e = 0; e < D_N; e += 4) {
    s0 += zs[r][e + 0] * wT[(e + 0) * M_N + m];
    s1 += zs[r][e + 1] * wT[(e + 1) * M_N + m];
    s2 += zs[r][e + 2] * wT[(e + 2) * M_N + m];
    s3 += zs[r][e + 3] * wT[(e + 3) * M_N + m];
  }
  float s = (s0 + s1) + (s2 + s3);
  float sig = 1.f / (1.f + expf(-s));
  gatesb[(b0 + r) * M_N + m] = (unsigned short)bf16_of(fmaxf(2.f * sig - 1.f, 0.f));
  #pragma unroll
  for (int j = 0; j < 4; ++j) {
    int idx = t + (j << 8);
    int rr = idx >> 6, blk = idx & 63;
    int chunk = blk >> 3, ib = blk & 7;
    int sb = ib ^ (rr & 7);
    const float* sp = &zs[rr][chunk * 64 + sb * 8];
    s16x8 o;
    #pragma unroll
    for (int k = 0; k < 8; ++k) o[k] = bf16_of(sp[k]);
    *(s16x8*)(zb + (b0 + rr) * D_N + blk * 8) = o;
  }
}

// ---------------------------------------------------------------------------
// Kernel 3: GEMM dz^T-tiles = sum_m g_m * (Psi_m^T @ z^T).  256(b)x128(e)
// block, 8 waves, d-OUTER / m-INNER (z frags reg-cached per d-chunk);
// Psi-side fragments pipelined in regs (bx/by ping-pong); ONE barrier per
// step; NBUF=4 B-buffers, counted vmcnt; first-MFMA C=0; gate prefetch one
// step ahead; gates f32 in LDS.  [R7 verbatim — compiler-chosen K-loop
// unroll is load-bearing: it folds (s&3) buffer indexing into immediates]
// ---------------------------------------------------------------------------
__global__ __launch_bounds__(512, 2) void k_gemm(
    const char* __restrict__ zb, const unsigned short* __restrict__ gatesb,
    const char* __restrict__ pb, float* __restrict__ dz) {
  // A bufs 2x32KB @0 | B bufs 4x16KB @65536 | gates f32 16KB @131072
  __shared__ __align__(128) char smem[147456];
  float* glf = (float*)(smem + 131072);

  const int tid = threadIdx.x;
  const int lane = tid & 63;
  const int wid = tid >> 6;
  const int wr = wid >> 1;             // b-block (64 rows of 256)
  const int wc = wid & 1;              // e-block (64 cols of 128)
  const int bid = blockIdx.x;
  const int xcd = bid & 7;
  const int g8 = bid >> 3;
  const int bcol = g8 & 3;
  const int brow = xcd * 8 + (g8 >> 2);  // A-centric XCD map (L2-resident z)

  // ---- gates -> LDS [m][256 rows] f32 (converted once here)
  {
    s16x8 gv = *(const s16x8*)(gatesb + ((size_t)brow << 12) + ((size_t)tid << 3));
    int row = tid >> 1, mbase = (tid & 1) << 3;
    #pragma unroll
    for (int k = 0; k < 8; ++k)
      glf[(mbase + k) * 256 + row] = f32_of_bf16((unsigned short)gv[k]);
  }

  const int rsub = lane >> 3, cbyte = (lane & 7) << 4;

  auto stageA = [&](int ab, int dc) {     // 4 loads: 256 rows x 128B d-chunk
    #pragma unroll
    for (int j = 0; j < 4; ++j) {
      const char* g = zb + (((size_t)(brow * 256 + wid * 8 + j * 64 + rsub)) << 10)
                      + (dc << 7) + cbyte;
      gload_lds16(g, smem + ab * 32768 + (wid << 10) + (j << 13));
    }
  };
  auto stageB = [&](int s) {              // 2 loads: 128 e-rows x 128B
    int m = s & 15, dc = s >> 4, q = s & 3;
    #pragma unroll
    for (int j = 0; j < 2; ++j) {
      const char* g = pb + (((size_t)(m * 512 + bcol * 128 + wid * 8 + j * 64 + rsub)) << 10)
                      + (dc << 7) + cbyte;
      gload_lds16(g, smem + 65536 + q * 16384 + (wid << 10) + (j << 13));
    }
  };

  const int lrow = lane & 15;
  const int swz = (lrow & 7) << 4;
  const int kq16 = (((lane >> 4) << 4)) ^ swz;
  const int offY = ((wr * 64 + lrow) << 7) + kq16;   // z frags (y operand)
  const int offX = ((wc * 64 + lrow) << 7) + kq16;   // Psi frags (x operand)
  const int grow = wr * 64 + lrow;                   // gate row base

  f32x4 acc[4][4] = {};
  f32x4 accm[4][4];
  s16x8 areg[4][2];
  s16x8 bx[4], by[4];
  float gjc[4], gjn[4];
  const f32x4 FZERO = {0.f, 0.f, 0.f, 0.f};

  // ---- prologue: A(dc0), B(0..2); drain; preload bx + gates for s=0
  stageA(0, 0);
  stageB(0); stageB(1); stageB(2);
  asm volatile("s_waitcnt vmcnt(0) lgkmcnt(0)" ::: "memory");
  __builtin_amdgcn_s_barrier();
  #pragma unroll
  for (int i = 0; i < 4; ++i)
    bx[i] = *(const s16x8*)(smem + 65536 + (offX + i * 2048));
  #pragma unroll
  for (int j = 0; j < 4; ++j)
    gjc[j] = glf[grow + j * 16];   // m=0

  for (int s = 0; s < 128; ++s) {
    const int m = s & 15, dc = s >> 4;
    const char* bbase_cur = smem + 65536 + (s & 3) * 16384;
    const char* bbase_nxt = smem + 65536 + ((s + 1) & 3) * 16384;

    // ---- reads for this step (z frags at dc start, ks1 Psi frags, next gates)
    if (m == 0) {
      const char* abase = smem + (dc & 1) * 32768;
      #pragma unroll
      for (int j = 0; j < 4; ++j) {
        areg[j][0] = *(const s16x8*)(abase + (offY + j * 2048));
        areg[j][1] = *(const s16x8*)(abase + ((offY + j * 2048) ^ 64));
      }
    }
    #pragma unroll
    for (int i = 0; i < 4; ++i)
      by[i] = *(const s16x8*)(bbase_cur + ((offX + i * 2048) ^ 64));
    {
      const int mn = (s + 1) & 15;
      #pragma unroll
      for (int j = 0; j < 4; ++j)
        gjn[j] = glf[mn * 256 + grow + j * 16];
    }
    if (s + 3 < 128) stageB(s + 3);
    if (m == 11 && dc < 7) stageA((dc & 1) ^ 1, dc + 1);

    // ---- section A: 16 MFMA, C = 0 (kills accm zeroing)
    __builtin_amdgcn_s_setprio(1);
    #pragma unroll
    for (int i = 0; i < 4; ++i)
      #pragma unroll
      for (int j = 0; j < 4; ++j)
        MFMA_Z(accm[i][j], bx[i], areg[j][0]);
    __builtin_amdgcn_s_setprio(0);

    // ---- read next step's ks0 Psi frags (hidden under section-B MFMAs)
    if (s < 127) {
      #pragma unroll
      for (int i = 0; i < 4; ++i)
        bx[i] = *(const s16x8*)(bbase_nxt + (offX + i * 2048));
    }

    // ---- section B: 16 MFMA accumulate, then gated fold (64 fma only)
    __builtin_amdgcn_s_setprio(1);
    #pragma unroll
    for (int i = 0; i < 4; ++i)
      #pragma unroll
      for (int j = 0; j < 4; ++j)
        MFMA_ACC(accm[i][j], by[i], areg[j][1]);
    __builtin_amdgcn_s_setprio(0);
    #pragma unroll
    for (int i = 0; i < 4; ++i)
      #pragma unroll
      for (int j = 0; j < 4; ++j)
        #pragma unroll
        for (int jj = 0; jj < 4; ++jj)
          acc[i][j][jj] = fmaf(gjc[j], accm[i][j][jj], acc[i][j][jj]);
    #pragma unroll
    for (int j = 0; j < 4; ++j) gjc[j] = gjn[j];

    if (dc < 7 && (m == 11 || m == 12))
      asm volatile("s_waitcnt vmcnt(6)" ::: "memory");   // A(dc+1)+2 B-tiles in flight
    else if (s >= 125)
      asm volatile("s_waitcnt vmcnt(0)" ::: "memory");   // epilogue drain
    else
      asm volatile("s_waitcnt vmcnt(2)" ::: "memory");   // B(s+2) landed, B(s+3) in flight
    __builtin_amdgcn_s_barrier();
  }

  // ---- epilogue: acc[i][j][jj] = dzT[e][b]
  #pragma unroll
  for (int i = 0; i < 4; ++i) {
    int e = bcol * 128 + wc * 64 + i * 16 + ((lane >> 4) << 2);
    #pragma unroll
    for (int j = 0; j < 4; ++j) {
      size_t b = (size_t)brow * 256 + wr * 64 + j * 16 + lrow;
      *(f32x4*)(dz + b * D_N + e) = acc[i][j];
    }
  }
}

// ---------------------------------------------------------------------------
extern "C" void kernel_launch(void* const* d_in, const int* in_sizes, int n_in,
                              void* d_out, int out_size, void* d_ws, size_t ws_size,
                              hipStream_t stream) {
  const float* z   = (const float*)d_in[1];
  const float* Psi = (const float*)d_in[2];
  const float* gt  = (const float*)d_in[3];
  float* dz = (float*)d_out;

  // ws: wT 32KB | gatesb 512KB | Psib 8MB | zb16 16MB  (~24.5MB)
  float* wT = (float*)d_ws;
  unsigned short* gatesb = (unsigned short*)((char*)d_ws + 32768);
  short* Psib = (short*)((char*)d_ws + 32768 + 524288);
  short* zb16 = Psib + (size_t)M_N * D_N * D_N;

  k_trw <<<dim3(8, M_N), dim3(256), 0, stream>>>(Psi, gt, Psib, wT);
  k_gz  <<<dim3(B_N / 16), dim3(256), 0, stream>>>(z, wT, zb16, gatesb);
  k_gemm<<<dim3(256), dim3(512), 0, stream>>>((const char*)zb16, gatesb,
                                              (const char*)Psib, dz);
}

// Round 16
// 153.699 us; speedup vs baseline: 1.2218x; 1.0090x over previous
//
#include <hip/hip_runtime.h>
#include <hip/hip_bf16.h>

#define B_N 16384
#define D_N 512
#define M_N 16

typedef __attribute__((ext_vector_type(4))) float  f32x4;
typedef __attribute__((ext_vector_type(8))) short  s16x8;

__device__ __forceinline__ short bf16_of(float f) {
  union { float f; unsigned u; } v; v.f = f;
  unsigned r = v.u + 0x7fffu + ((v.u >> 16) & 1u);  // RNE
  return (short)(r >> 16);
}
__device__ __forceinline__ float f32_of_bf16(unsigned short u) {
  union { unsigned u; float f; } v; v.u = ((unsigned)u) << 16; return v.f;
}
__device__ __forceinline__ void gload_lds16(const void* g, void* l) {
  __builtin_amdgcn_global_load_lds(
      (const __attribute__((address_space(1))) unsigned*)g,
      (__attribute__((address_space(3))) unsigned*)l, 16, 0, 0);
}

#define MFMA_ACC(d, x, y) d = __builtin_amdgcn_mfma_f32_16x16x32_bf16(x, y, d, 0, 0, 0)
#define MFMA_Z(d, x, y)   d = __builtin_amdgcn_mfma_f32_16x16x32_bf16(x, y, FZERO, 0, 0, 0)

// ---------------------------------------------------------------------------
// Kernel 1a: wT[d,m] = sum_e Psi[m,d,e]*gt[m,e]  (f32 exact path for gates).
// grid (16 m, 32 d-tiles) x 256: 512 blocks, 16 d-rows each, wave per row.
// ---------------------------------------------------------------------------
__global__ void k_w(const float* __restrict__ Psi, const float* __restrict__ gt,
                    float* __restrict__ wT) {
  int m = blockIdx.x;
  int d0 = blockIdx.y * 16;
  __shared__ float g[D_N];
  for (int i = threadIdx.x; i < D_N; i += 256) g[i] = gt[m * D_N + i];
  __syncthreads();
  int wave = threadIdx.x >> 6, lane = threadIdx.x & 63;
  #pragma unroll
  for (int d = d0 + wave; d < d0 + 16; d += 4) {
    const float* row = Psi + ((size_t)m * D_N + d) * D_N;
    const f32x4* r4 = (const f32x4*)(row + lane * 8);
    const f32x4* g4 = (const f32x4*)(g + lane * 8);
    f32x4 a0 = r4[0], a1 = r4[1];
    f32x4 b0 = g4[0], b1 = g4[1];
    float s = a0[0]*b0[0] + a0[1]*b0[1] + a0[2]*b0[2] + a0[3]*b0[3]
            + a1[0]*b1[0] + a1[1]*b1[1] + a1[2]*b1[2] + a1[3]*b1[3];
    #pragma unroll
    for (int off = 32; off; off >>= 1) s += __shfl_down(s, off);
    if (lane == 0) wT[d * M_N + m] = s;
  }
}

// ---------------------------------------------------------------------------
// Kernel 1b: Psib[m][e][d] = bf16(Psi[m][d][e]) with per-e-row (e&7)
// pre-swizzle (16B-block XOR within each 128B chunk).  Pure transpose,
// grid (8 d-tiles, 8 e-tiles, 16 m) x 256 = 1024 blocks, one barrier.
// ---------------------------------------------------------------------------
__global__ void k_tr(const float* __restrict__ Psi, short* __restrict__ Psib) {
  int m = blockIdx.z, d0 = blockIdx.x << 6, e0 = blockIdx.y << 6;
  __shared__ float tile[64][65];
  int t = threadIdx.x;
  const float* src = Psi + (size_t)m * D_N * D_N;
  short* dst = Psib + (size_t)m * D_N * D_N;
  #pragma unroll
  for (int j = 0; j < 4; ++j) {
    int idx = t + (j << 8);
    int rr = idx >> 4, c4 = idx & 15;
    *(f32x4*)&tile[rr][c4 * 4] = *(const f32x4*)(src + (size_t)(d0 + rr) * D_N + e0 + c4 * 4);
  }
  __syncthreads();
  #pragma unroll
  for (int it = 0; it < 2; ++it) {
    int idx = t + (it << 8);
    int el = idx >> 3, jb = idx & 7;
    int e = e0 + el;
    s16x8 o;
    #pragma unroll
    for (int k = 0; k < 8; ++k) o[k] = bf16_of(tile[jb * 8 + k][el]);
    int db = jb ^ (e & 7);
    *(s16x8*)(dst + (size_t)e * D_N + d0 + db * 8) = o;
  }
}

// ---------------------------------------------------------------------------
// Kernel 2 (fused): gates (bf16) + pre-swizzled bf16 z, one z read.
// ---------------------------------------------------------------------------
__global__ void k_gz(const float* __restrict__ z, const float* __restrict__ wT,
                     short* __restrict__ zb, unsigned short* __restrict__ gatesb) {
  __shared__ float zs[16][D_N];
  int t = threadIdx.x;
  size_t b0 = (size_t)blockIdx.x * 16;
  #pragma unroll
  for (int j = 0; j < 8; ++j) {
    int idx = t + (j << 8);
    int r = idx >> 7, c4 = idx & 127;
    *(f32x4*)&zs[r][c4 * 4] = *(const f32x4*)(z + (b0 + r) * D_N + c4 * 4);
  }
  __syncthreads();
  int r = t >> 4, m = t & 15;
  float s0 = 0.f, s1 = 0.f, s2 = 0.f, s3 = 0.f;
  #pragma unroll 4
  for (int e = 0; e < D_N; e += 4) {
    s0 += zs[r][e + 0] * wT[(e + 0) * M_N + m];
    s1 += zs[r][e + 1] * wT[(e + 1) * M_N + m];
    s2 += zs[r][e + 2] * wT[(e + 2) * M_N + m];
    s3 += zs[r][e + 3] * wT[(e + 3) * M_N + m];
  }
  float s = (s0 + s1) + (s2 + s3);
  float sig = 1.f / (1.f + expf(-s));
  gatesb[(b0 + r) * M_N + m] = (unsigned short)bf16_of(fmaxf(2.f * sig - 1.f, 0.f));
  #pragma unroll
  for (int j = 0; j < 4; ++j) {
    int idx = t + (j << 8);
    int rr = idx >> 6, blk = idx & 63;
    int chunk = blk >> 3, ib = blk & 7;
    int sb = ib ^ (rr & 7);
    const float* sp = &zs[rr][chunk * 64 + sb * 8];
    s16x8 o;
    #pragma unroll
    for (int k = 0; k < 8; ++k) o[k] = bf16_of(sp[k]);
    *(s16x8*)(zb + (b0 + rr) * D_N + blk * 8) = o;
  }
}

// ---------------------------------------------------------------------------
// Kernel 3: GEMM dz^T-tiles = sum_m g_m * (Psi_m^T @ z^T).  256(b)x128(e)
// block, 8 waves, d-OUTER / m-INNER (z frags reg-cached per d-chunk);
// Psi-side fragments pipelined in regs (bx/by ping-pong); ONE barrier per
// step; NBUF=4 B-buffers, counted vmcnt; first-MFMA C=0; gate prefetch one
// step ahead; gates f32 in LDS.  [R7/R15 verbatim — session-best GEMM;
// compiler-chosen K-loop unroll is load-bearing]
// ---------------------------------------------------------------------------
__global__ __launch_bounds__(512, 2) void k_gemm(
    const char* __restrict__ zb, const unsigned short* __restrict__ gatesb,
    const char* __restrict__ pb, float* __restrict__ dz) {
  // A bufs 2x32KB @0 | B bufs 4x16KB @65536 | gates f32 16KB @131072
  __shared__ __align__(128) char smem[147456];
  float* glf = (float*)(smem + 131072);

  const int tid = threadIdx.x;
  const int lane = tid & 63;
  const int wid = tid >> 6;
  const int wr = wid >> 1;             // b-block (64 rows of 256)
  const int wc = wid & 1;              // e-block (64 cols of 128)
  const int bid = blockIdx.x;
  const int xcd = bid & 7;
  const int g8 = bid >> 3;
  const int bcol = g8 & 3;
  const int brow = xcd * 8 + (g8 >> 2);  // A-centric XCD map (L2-resident z)

  // ---- gates -> LDS [m][256 rows] f32 (converted once here)
  {
    s16x8 gv = *(const s16x8*)(gatesb + ((size_t)brow << 12) + ((size_t)tid << 3));
    int row = tid >> 1, mbase = (tid & 1) << 3;
    #pragma unroll
    for (int k = 0; k < 8; ++k)
      glf[(mbase + k) * 256 + row] = f32_of_bf16((unsigned short)gv[k]);
  }

  const int rsub = lane >> 3, cbyte = (lane & 7) << 4;

  auto stageA = [&](int ab, int dc) {     // 4 loads: 256 rows x 128B d-chunk
    #pragma unroll
    for (int j = 0; j < 4; ++j) {
      const char* g = zb + (((size_t)(brow * 256 + wid * 8 + j * 64 + rsub)) << 10)
                      + (dc << 7) + cbyte;
      gload_lds16(g, smem + ab * 32768 + (wid << 10) + (j << 13));
    }
  };
  auto stageB = [&](int s) {              // 2 loads: 128 e-rows x 128B
    int m = s & 15, dc = s >> 4, q = s & 3;
    #pragma unroll
    for (int j = 0; j < 2; ++j) {
      const char* g = pb + (((size_t)(m * 512 + bcol * 128 + wid * 8 + j * 64 + rsub)) << 10)
                      + (dc << 7) + cbyte;
      gload_lds16(g, smem + 65536 + q * 16384 + (wid << 10) + (j << 13));
    }
  };

  const int lrow = lane & 15;
  const int swz = (lrow & 7) << 4;
  const int kq16 = (((lane >> 4) << 4)) ^ swz;
  const int offY = ((wr * 64 + lrow) << 7) + kq16;   // z frags (y operand)
  const int offX = ((wc * 64 + lrow) << 7) + kq16;   // Psi frags (x operand)
  const int grow = wr * 64 + lrow;                   // gate row base

  f32x4 acc[4][4] = {};
  f32x4 accm[4][4];
  s16x8 areg[4][2];
  s16x8 bx[4], by[4];
  float gjc[4], gjn[4];
  const f32x4 FZERO = {0.f, 0.f, 0.f, 0.f};

  // ---- prologue: A(dc0), B(0..2); drain; preload bx + gates for s=0
  stageA(0, 0);
  stageB(0); stageB(1); stageB(2);
  asm volatile("s_waitcnt vmcnt(0) lgkmcnt(0)" ::: "memory");
  __builtin_amdgcn_s_barrier();
  #pragma unroll
  for (int i = 0; i < 4; ++i)
    bx[i] = *(const s16x8*)(smem + 65536 + (offX + i * 2048));
  #pragma unroll
  for (int j = 0; j < 4; ++j)
    gjc[j] = glf[grow + j * 16];   // m=0

  for (int s = 0; s < 128; ++s) {
    const int m = s & 15, dc = s >> 4;
    const char* bbase_cur = smem + 65536 + (s & 3) * 16384;
    const char* bbase_nxt = smem + 65536 + ((s + 1) & 3) * 16384;

    // ---- reads for this step (z frags at dc start, ks1 Psi frags, next gates)
    if (m == 0) {
      const char* abase = smem + (dc & 1) * 32768;
      #pragma unroll
      for (int j = 0; j < 4; ++j) {
        areg[j][0] = *(const s16x8*)(abase + (offY + j * 2048));
        areg[j][1] = *(const s16x8*)(abase + ((offY + j * 2048) ^ 64));
      }
    }
    #pragma unroll
    for (int i = 0; i < 4; ++i)
      by[i] = *(const s16x8*)(bbase_cur + ((offX + i * 2048) ^ 64));
    {
      const int mn = (s + 1) & 15;
      #pragma unroll
      for (int j = 0; j < 4; ++j)
        gjn[j] = glf[mn * 256 + grow + j * 16];
    }
    if (s + 3 < 128) stageB(s + 3);
    if (m == 11 && dc < 7) stageA((dc & 1) ^ 1, dc + 1);

    // ---- section A: 16 MFMA, C = 0 (kills accm zeroing)
    __builtin_amdgcn_s_setprio(1);
    #pragma unroll
    for (int i = 0; i < 4; ++i)
      #pragma unroll
      for (int j = 0; j < 4; ++j)
        MFMA_Z(accm[i][j], bx[i], areg[j][0]);
    __builtin_amdgcn_s_setprio(0);

    // ---- read next step's ks0 Psi frags (hidden under section-B MFMAs)
    if (s < 127) {
      #pragma unroll
      for (int i = 0; i < 4; ++i)
        bx[i] = *(const s16x8*)(bbase_nxt + (offX + i * 2048));
    }

    // ---- section B: 16 MFMA accumulate, then gated fold (64 fma only)
    __builtin_amdgcn_s_setprio(1);
    #pragma unroll
    for (int i = 0; i < 4; ++i)
      #pragma unroll
      for (int j = 0; j < 4; ++j)
        MFMA_ACC(accm[i][j], by[i], areg[j][1]);
    __builtin_amdgcn_s_setprio(0);
    #pragma unroll
    for (int i = 0; i < 4; ++i)
      #pragma unroll
      for (int j = 0; j < 4; ++j)
        #pragma unroll
        for (int jj = 0; jj < 4; ++jj)
          acc[i][j][jj] = fmaf(gjc[j], accm[i][j][jj], acc[i][j][jj]);
    #pragma unroll
    for (int j = 0; j < 4; ++j) gjc[j] = gjn[j];

    if (dc < 7 && (m == 11 || m == 12))
      asm volatile("s_waitcnt vmcnt(6)" ::: "memory");   // A(dc+1)+2 B-tiles in flight
    else if (s >= 125)
      asm volatile("s_waitcnt vmcnt(0)" ::: "memory");   // epilogue drain
    else
      asm volatile("s_waitcnt vmcnt(2)" ::: "memory");   // B(s+2) landed, B(s+3) in flight
    __builtin_amdgcn_s_barrier();
  }

  // ---- epilogue: acc[i][j][jj] = dzT[e][b]
  #pragma unroll
  for (int i = 0; i < 4; ++i) {
    int e = bcol * 128 + wc * 64 + i * 16 + ((lane >> 4) << 2);
    #pragma unroll
    for (int j = 0; j < 4; ++j) {
      size_t b = (size_t)brow * 256 + wr * 64 + j * 16 + lrow;
      *(f32x4*)(dz + b * D_N + e) = acc[i][j];
    }
  }
}

// ---------------------------------------------------------------------------
extern "C" void kernel_launch(void* const* d_in, const int* in_sizes, int n_in,
                              void* d_out, int out_size, void* d_ws, size_t ws_size,
                              hipStream_t stream) {
  const float* z   = (const float*)d_in[1];
  const float* Psi = (const float*)d_in[2];
  const float* gt  = (const float*)d_in[3];
  float* dz = (float*)d_out;

  // ws: wT 32KB | gatesb 512KB | Psib 8MB | zb16 16MB  (~24.5MB)
  float* wT = (float*)d_ws;
  unsigned short* gatesb = (unsigned short*)((char*)d_ws + 32768);
  short* Psib = (short*)((char*)d_ws + 32768 + 524288);
  short* zb16 = Psib + (size_t)M_N * D_N * D_N;

  k_w   <<<dim3(M_N, 32),   dim3(256), 0, stream>>>(Psi, gt, wT);
  k_tr  <<<dim3(8, 8, M_N), dim3(256), 0, stream>>>(Psi, Psib);
  k_gz  <<<dim3(B_N / 16),  dim3(256), 0, stream>>>(z, wT, zb16, gatesb);
  k_gemm<<<dim3(256),       dim3(512), 0, stream>>>((const char*)zb16, gatesb,
                                                    (const char*)Psib, dz);
}